// Round 6
// baseline (1132.214 us; speedup 1.0000x reference)
//
#include <hip/hip_runtime.h>
#include <hip/hip_bf16.h>

// ---------------------------------------------------------------------------
// B=8, NT=32, NO=8, C=512, VD=1024, RD=300; No=512, Nr=2048.
// r-chain: split-bf16 (hi/lo planes) MFMA, ~fp32 accurate, planes carried in
// memory end-to-end (incl. one-shot Ar pre-split). Round-6:
//  - gemm_planes: T4 counted-vmcnt pipeline. Raw s_barrier + inline-asm
//    s_waitcnt vmcnt(8): tile t+1's 8 global_load_lds stay IN FLIGHT across
//    the barrier (never drained to 0 in steady state). Loads get a full
//    K-step (~700 cyc) of latency budget instead of the ~480-cyc compute
//    phase. 2 buffers, 2 barriers/K-step; STAGE t+2 issued right after the
//    end-of-compute barrier into the just-freed buffer.
//  - Keeps round-4/5: both-sides XOR swizzle (bank-conflict = 0 verified),
//    XCD-aware bijective block swizzle, zero-VGPR DMA staging.
// o-branch + epilogue: plain bf16 MFMA (round-1 structure). Output fp32.
// ---------------------------------------------------------------------------

typedef __attribute__((ext_vector_type(4))) float f32x4;
typedef __attribute__((ext_vector_type(8))) short bf16x8s;

#define TILE 128
#define BKK 32
#define LDSS 40  // padded stride for the sync-staged kernels (asplit/bf16)
#define LDSL 32  // linear stride for global_load_lds staged gemm_planes

#if __has_builtin(__builtin_amdgcn_global_load_lds)
#define HAVE_GLL 1
#else
#define HAVE_GLL 0
#endif

__device__ inline void gll16(const __hip_bfloat16* g, __hip_bfloat16* l) {
#if HAVE_GLL
    __builtin_amdgcn_global_load_lds(
        (const __attribute__((address_space(1))) void*)g,
        (__attribute__((address_space(3))) void*)l,
        16, 0, 0);
#endif
}

__device__ inline void split2(float a, float b, unsigned& h, unsigned& l) {
    __hip_bfloat16 ha = __float2bfloat16(a), hb = __float2bfloat16(b);
    float ra = __bfloat162float(ha), rb = __bfloat162float(hb);
    __hip_bfloat16 la = __float2bfloat16(a - ra), lb = __float2bfloat16(b - rb);
    unsigned short uha = *(unsigned short*)&ha, uhb = *(unsigned short*)&hb;
    unsigned short ula = *(unsigned short*)&la, ulb = *(unsigned short*)&lb;
    h = (unsigned)uha | ((unsigned)uhb << 16);
    l = (unsigned)ula | ((unsigned)ulb << 16);
}

__device__ inline void splitw(float v, unsigned short& h, unsigned short& l) {
    __hip_bfloat16 hb = __float2bfloat16(v);
    __hip_bfloat16 lb = __float2bfloat16(v - __bfloat162float(hb));
    h = *(unsigned short*)&hb;
    l = *(unsigned short*)&lb;
}

// XCD-aware bijective block swizzle (all grids here have nwg % 8 == 0).
__device__ inline void swz_block(int& bx, int& by, int& bz) {
    int gx = gridDim.x, gy = gridDim.y;
    int nwg = gx * gy * gridDim.z;
    int flat = bx + gx * (by + gy * bz);
    int cpx = nwg >> 3;
    int w = (flat & 7) * cpx + (flat >> 3);
    bx = w % gx;
    int t = w / gx;
    by = t % gy;
    bz = t / gy;
}

// ---------------- GEMM: both A and B pre-split planes, counted-vmcnt --------
// D = act(A@B + addN + (addTh+addTl)^T + bias).
// Ah/Al:(batch,M,K) planes, BTh/BTl:(batch,N,K) planes (B transposed).
// outMode: 0 = fp32 D; 1 = hi/lo planes (D = hi base, Dl_ = lo base).
__global__ __launch_bounds__(256) void gemm_planes(
    const __hip_bfloat16* __restrict__ Aph, const __hip_bfloat16* __restrict__ Apl,
    long long sA, int lda,
    const __hip_bfloat16* __restrict__ BTh, const __hip_bfloat16* __restrict__ BTl,
    long long sBT, int ldbt,
    void* __restrict__ D, __hip_bfloat16* __restrict__ Dl_, long long sD, int ldd,
    const float* __restrict__ addN, long long sAddN, int ldaddN,
    const __hip_bfloat16* __restrict__ addTh, const __hip_bfloat16* __restrict__ addTl,
    long long sAddT, int ldaddT,
    const float* __restrict__ bias,
    int K, int relu, int outMode)
{
    // Double-buffered linear LDS tiles (2 x 128 x 32 halfs = 8KB each plane).
    // Physical slot (m,s) holds logical column block (s ^ g(m)), g(m)=(m>>1)&3.
    __shared__ __hip_bfloat16 AhB[2][TILE * LDSL], AlB[2][TILE * LDSL];
    __shared__ __hip_bfloat16 BhB[2][TILE * LDSL], BlB[2][TILE * LDSL];

    int bx = blockIdx.x, by = blockIdx.y, bz = blockIdx.z;
    swz_block(bx, by, bz);

    const int tid  = threadIdx.x;
    const int lane = tid & 63;
    const int wave = tid >> 6;
    const int wm   = (wave >> 1) * 64;
    const int wn   = (wave & 1) * 64;
    const int row0 = by * TILE;
    const int col0 = bx * TILE;
    const int b    = bz;

    const __hip_bfloat16* Abh = Aph + (size_t)b * sA;
    const __hip_bfloat16* Abl = Apl + (size_t)b * sA;
    const __hip_bfloat16* Bbh = BTh + (size_t)b * sBT;
    const __hip_bfloat16* Bbl = BTl + (size_t)b * sBT;

    f32x4 acc[4][4];
#pragma unroll
    for (int i = 0; i < 4; ++i)
#pragma unroll
        for (int j = 0; j < 4; ++j) acc[i][j] = (f32x4){0.f, 0.f, 0.f, 0.f};

    const int quad = lane >> 4;
    const int l16  = lane & 15;

    // Staging geometry: each wave DMAs 2 chunks (c = wave, wave+4) per plane.
    // Chunk c = 16 rows; lane covers (m = c*16 + lane>>2, slot s = lane&3),
    // loading logical column block kq = s ^ g(m) (pre-swizzled source).
    const int m0  = wave * 16 + (lane >> 2);
    const int m1  = (wave + 4) * 16 + (lane >> 2);
    const int sl  = lane & 3;
    const int kq0 = sl ^ ((m0 >> 1) & 3);
    const int kq1 = sl ^ ((m1 >> 1) & 3);
    const size_t gA0 = (size_t)(row0 + m0) * lda + kq0 * 8;
    const size_t gA1 = (size_t)(row0 + m1) * lda + kq1 * 8;
    const size_t gB0 = (size_t)(col0 + m0) * ldbt + kq0 * 8;
    const size_t gB1 = (size_t)(col0 + m1) * ldbt + kq1 * 8;
    const int ldsc0 = wave * 512;        // chunk half-offsets (1024B / 2)
    const int ldsc1 = (wave + 4) * 512;

#if HAVE_GLL
#define STAGE(buf, kk) do { \
    gll16(Abh + gA0 + (kk), &AhB[buf][ldsc0]); \
    gll16(Abh + gA1 + (kk), &AhB[buf][ldsc1]); \
    gll16(Abl + gA0 + (kk), &AlB[buf][ldsc0]); \
    gll16(Abl + gA1 + (kk), &AlB[buf][ldsc1]); \
    gll16(Bbh + gB0 + (kk), &BhB[buf][ldsc0]); \
    gll16(Bbh + gB1 + (kk), &BhB[buf][ldsc1]); \
    gll16(Bbl + gB0 + (kk), &BlB[buf][ldsc0]); \
    gll16(Bbl + gB1 + (kk), &BlB[buf][ldsc1]); \
} while (0)
#else
#define STAGE(buf, kk) do { \
    *(uint4*)(&AhB[buf][m0 * LDSL + sl * 8]) = *(const uint4*)(Abh + gA0 + (kk)); \
    *(uint4*)(&AhB[buf][m1 * LDSL + sl * 8]) = *(const uint4*)(Abh + gA1 + (kk)); \
    *(uint4*)(&AlB[buf][m0 * LDSL + sl * 8]) = *(const uint4*)(Abl + gA0 + (kk)); \
    *(uint4*)(&AlB[buf][m1 * LDSL + sl * 8]) = *(const uint4*)(Abl + gA1 + (kk)); \
    *(uint4*)(&BhB[buf][m0 * LDSL + sl * 8]) = *(const uint4*)(Bbh + gB0 + (kk)); \
    *(uint4*)(&BhB[buf][m1 * LDSL + sl * 8]) = *(const uint4*)(Bbh + gB1 + (kk)); \
    *(uint4*)(&BlB[buf][m0 * LDSL + sl * 8]) = *(const uint4*)(Bbl + gB0 + (kk)); \
    *(uint4*)(&BlB[buf][m1 * LDSL + sl * 8]) = *(const uint4*)(Bbl + gB1 + (kk)); \
} while (0)
#endif

#if HAVE_GLL
#define WAITVM8() asm volatile("s_waitcnt vmcnt(8)" ::: "memory")
#define WAITVM0() asm volatile("s_waitcnt vmcnt(0)" ::: "memory")
#else
#define WAITVM8() asm volatile("" ::: "memory")
#define WAITVM0() asm volatile("" ::: "memory")
#endif

    const int nt = K / BKK;   // >= 2 for all call sites (min K = 320)
    int cur = 0;

    STAGE(0, 0);
    STAGE(1, BKK);            // two tiles in flight (16 loads/wave)

    for (int t = 0; t < nt; ++t) {
        // Counted wait: tile t's 8 loads landed; tile t+1's stay in flight.
        if (t + 1 < nt) { WAITVM8(); } else { WAITVM0(); }
        __builtin_amdgcn_s_barrier();   // publish: every wave's tile-t chunks ready

        const __hip_bfloat16* Ah = AhB[cur];
        const __hip_bfloat16* Al = AlB[cur];
        const __hip_bfloat16* Bh = BhB[cur];
        const __hip_bfloat16* Bl = BlB[cur];

        bf16x8s bhf[4], blf[4];
#pragma unroll
        for (int nt2 = 0; nt2 < 4; ++nt2) {
            int r = wn + nt2 * 16 + l16;
            int ss = (quad ^ ((r >> 1) & 3)) * 8;
            bhf[nt2] = *(const bf16x8s*)(&Bh[r * LDSL + ss]);
            blf[nt2] = *(const bf16x8s*)(&Bl[r * LDSL + ss]);
        }
#pragma unroll
        for (int mt = 0; mt < 4; ++mt) {
            int r = wm + mt * 16 + l16;
            int ss = (quad ^ ((r >> 1) & 3)) * 8;
            bf16x8s ahf = *(const bf16x8s*)(&Ah[r * LDSL + ss]);
            bf16x8s alf = *(const bf16x8s*)(&Al[r * LDSL + ss]);
#pragma unroll
            for (int nt2 = 0; nt2 < 4; ++nt2) {
                acc[mt][nt2] = __builtin_amdgcn_mfma_f32_16x16x32_bf16(ahf, bhf[nt2], acc[mt][nt2], 0, 0, 0);
                acc[mt][nt2] = __builtin_amdgcn_mfma_f32_16x16x32_bf16(ahf, blf[nt2], acc[mt][nt2], 0, 0, 0);
                acc[mt][nt2] = __builtin_amdgcn_mfma_f32_16x16x32_bf16(alf, bhf[nt2], acc[mt][nt2], 0, 0, 0);
            }
        }

        // All ds_read values above are consumed by MFMAs (compiler inserts
        // lgkmcnt waits), so after this barrier every wave is done reading
        // buf cur — safe to re-stage it.
        __builtin_amdgcn_s_barrier();
        if (t + 2 < nt) STAGE(cur, (t + 2) * BKK);
        cur ^= 1;
    }
#undef STAGE
#undef WAITVM8
#undef WAITVM0

    float* DbF = (float*)D + (size_t)b * sD;
    __hip_bfloat16* Dhb = (__hip_bfloat16*)D + (size_t)b * sD;
    __hip_bfloat16* Dlb = Dl_ ? Dl_ + (size_t)b * sD : nullptr;
    const float* AddN = addN ? addN + (size_t)b * sAddN : nullptr;
    const __hip_bfloat16* ATh = addTh ? addTh + (size_t)b * sAddT : nullptr;
    const __hip_bfloat16* ATl = addTl ? addTl + (size_t)b * sAddT : nullptr;
#pragma unroll
    for (int mt = 0; mt < 4; ++mt)
#pragma unroll
        for (int nt2 = 0; nt2 < 4; ++nt2)
#pragma unroll
            for (int r = 0; r < 4; ++r) {
                int m = row0 + wm + mt * 16 + quad * 4 + r;
                int n = col0 + wn + nt2 * 16 + l16;
                float v = acc[mt][nt2][r];
                if (AddN) v += AddN[(size_t)m * ldaddN + n];
                if (ATh) v += __bfloat162float(ATh[(size_t)n * ldaddT + m])
                            + __bfloat162float(ATl[(size_t)n * ldaddT + m]);
                if (bias) v += bias[n];
                if (relu && v < 0.f) v = 0.f;
                if (outMode == 0) {
                    DbF[(size_t)m * ldd + n] = v;
                } else {
                    unsigned short hh, ll;
                    splitw(v, hh, ll);
                    size_t o = (size_t)m * ldd + n;
                    *(unsigned short*)&Dhb[o] = hh;
                    *(unsigned short*)&Dlb[o] = ll;
                }
            }
}

// ---------------- GEMM: A fp32 (in-loop split), B planes (fallback) ---------
// Round-1 structure (sync staging, padded LDS). Only used if Ar planes
// don't fit in workspace.
__global__ __launch_bounds__(256) void gemm_asplit(
    const float* __restrict__ A, long long sA, int lda,
    const __hip_bfloat16* __restrict__ BTh, const __hip_bfloat16* __restrict__ BTl,
    long long sBT, int ldbt,
    __hip_bfloat16* __restrict__ Dh_, __hip_bfloat16* __restrict__ Dl_,
    long long sD, int ldd,
    const float* __restrict__ addN, long long sAddN, int ldaddN,
    const __hip_bfloat16* __restrict__ addTh, const __hip_bfloat16* __restrict__ addTl,
    long long sAddT, int ldaddT,
    int K, int relu)
{
    __shared__ __hip_bfloat16 Ah[TILE * LDSS], Al[TILE * LDSS];
    __shared__ __hip_bfloat16 Bh[TILE * LDSS], Bl[TILE * LDSS];

    const int tid  = threadIdx.x;
    const int lane = tid & 63;
    const int wave = tid >> 6;
    const int wm   = (wave >> 1) * 64;
    const int wn   = (wave & 1) * 64;
    const int row0 = blockIdx.y * TILE;
    const int col0 = blockIdx.x * TILE;
    const int b    = blockIdx.z;

    const float* Ab = A + (size_t)b * sA;
    const __hip_bfloat16* Bbh = BTh + (size_t)b * sBT;
    const __hip_bfloat16* Bbl = BTl + (size_t)b * sBT;

    f32x4 acc[4][4];
#pragma unroll
    for (int i = 0; i < 4; ++i)
#pragma unroll
        for (int j = 0; j < 4; ++j) acc[i][j] = (f32x4){0.f, 0.f, 0.f, 0.f};

    const int quad = lane >> 4;
    const int l16  = lane & 15;

    for (int k0 = 0; k0 < K; k0 += BKK) {
        __syncthreads();
#pragma unroll
        for (int it = 0; it < 2; ++it) {
            int task = tid + it * 256;
            int m = task >> 2, kq = task & 3;
            const float* ap = Ab + (size_t)(row0 + m) * lda + k0 + kq * 8;
            float4 v0 = *(const float4*)ap;
            float4 v1 = *(const float4*)(ap + 4);
            uint4 H, L;
            split2(v0.x, v0.y, H.x, L.x); split2(v0.z, v0.w, H.y, L.y);
            split2(v1.x, v1.y, H.z, L.z); split2(v1.z, v1.w, H.w, L.w);
            *(uint4*)(&Ah[m * LDSS + kq * 8]) = H;
            *(uint4*)(&Al[m * LDSS + kq * 8]) = L;
        }
#pragma unroll
        for (int it = 0; it < 2; ++it) {
            int task = tid + it * 256;
            int n = task >> 2, kq = task & 3;
            size_t off = (size_t)(col0 + n) * ldbt + k0 + kq * 8;
            *(uint4*)(&Bh[n * LDSS + kq * 8]) = *(const uint4*)(Bbh + off);
            *(uint4*)(&Bl[n * LDSS + kq * 8]) = *(const uint4*)(Bbl + off);
        }
        __syncthreads();

        bf16x8s ah[4], al[4], bh[4], bl[4];
#pragma unroll
        for (int mt = 0; mt < 4; ++mt) {
            int r = (wm + mt * 16 + l16) * LDSS + quad * 8;
            ah[mt] = *(const bf16x8s*)(&Ah[r]);
            al[mt] = *(const bf16x8s*)(&Al[r]);
        }
#pragma unroll
        for (int nt = 0; nt < 4; ++nt) {
            int r = (wn + nt * 16 + l16) * LDSS + quad * 8;
            bh[nt] = *(const bf16x8s*)(&Bh[r]);
            bl[nt] = *(const bf16x8s*)(&Bl[r]);
        }
#pragma unroll
        for (int mt = 0; mt < 4; ++mt)
#pragma unroll
            for (int nt = 0; nt < 4; ++nt) {
                acc[mt][nt] = __builtin_amdgcn_mfma_f32_16x16x32_bf16(ah[mt], bh[nt], acc[mt][nt], 0, 0, 0);
                acc[mt][nt] = __builtin_amdgcn_mfma_f32_16x16x32_bf16(ah[mt], bl[nt], acc[mt][nt], 0, 0, 0);
                acc[mt][nt] = __builtin_amdgcn_mfma_f32_16x16x32_bf16(al[mt], bh[nt], acc[mt][nt], 0, 0, 0);
            }
    }

    __hip_bfloat16* Dhb = Dh_ + (size_t)b * sD;
    __hip_bfloat16* Dlb = Dl_ + (size_t)b * sD;
    const float* AddN = addN ? addN + (size_t)b * sAddN : nullptr;
    const __hip_bfloat16* ATh = addTh ? addTh + (size_t)b * sAddT : nullptr;
    const __hip_bfloat16* ATl = addTl ? addTl + (size_t)b * sAddT : nullptr;
#pragma unroll
    for (int mt = 0; mt < 4; ++mt)
#pragma unroll
        for (int nt = 0; nt < 4; ++nt)
#pragma unroll
            for (int r = 0; r < 4; ++r) {
                int m = row0 + wm + mt * 16 + quad * 4 + r;
                int n = col0 + wn + nt * 16 + l16;
                float v = acc[mt][nt][r];
                if (AddN) v += AddN[(size_t)m * ldaddN + n];
                if (ATh) v += __bfloat162float(ATh[(size_t)n * ldaddT + m])
                            + __bfloat162float(ATl[(size_t)n * ldaddT + m]);
                if (relu && v < 0.f) v = 0.f;
                unsigned short hh, ll;
                splitw(v, hh, ll);
                size_t o = (size_t)m * ldd + n;
                *(unsigned short*)&Dhb[o] = hh;
                *(unsigned short*)&Dlb[o] = ll;
            }
}

// ---------------- tiled fp32 transpose with zero-pad -> hi/lo planes --------
__global__ __launch_bounds__(256) void padtrans_split(
    const float* __restrict__ src,
    __hip_bfloat16* __restrict__ dsth, __hip_bfloat16* __restrict__ dstl,
    int R, int C, int Rp, int Cp)
{
    __shared__ float T[64][65];
    const int t = threadIdx.x;
    const int tr = t >> 4, tc = t & 15;
    const int c0 = blockIdx.x * 64, r0 = blockIdx.y * 64;
    const size_t bat = blockIdx.z;
    const float* sb = src + bat * (size_t)R * C;
    __hip_bfloat16* dhb = dsth + bat * (size_t)Cp * Rp;
    __hip_bfloat16* dlb = dstl + bat * (size_t)Cp * Rp;

#pragma unroll
    for (int i = 0; i < 4; ++i) {
        int rr = tr + i * 16;
        int gr = r0 + rr;
        float v0 = 0.f, v1 = 0.f, v2 = 0.f, v3 = 0.f;
        if (gr < R) {
            int c = c0 + tc * 4;
            const float* s = sb + (size_t)gr * C + c;
            if (c + 0 < C) v0 = s[0];
            if (c + 1 < C) v1 = s[1];
            if (c + 2 < C) v2 = s[2];
            if (c + 3 < C) v3 = s[3];
        }
        T[rr][tc * 4 + 0] = v0; T[rr][tc * 4 + 1] = v1;
        T[rr][tc * 4 + 2] = v2; T[rr][tc * 4 + 3] = v3;
    }
    __syncthreads();
#pragma unroll
    for (int i = 0; i < 4; ++i) {
        int cc = tr + i * 16;
        float4 v = { T[tc * 4 + 0][cc], T[tc * 4 + 1][cc],
                     T[tc * 4 + 2][cc], T[tc * 4 + 3][cc] };
        ushort4 H, L;
        splitw(v.x, H.x, L.x); splitw(v.y, H.y, L.y);
        splitw(v.z, H.z, L.z); splitw(v.w, H.w, L.w);
        size_t off = (size_t)(c0 + cc) * Rp + r0 + tc * 4;
        *(ushort4*)(dhb + off) = H;
        *(ushort4*)(dlb + off) = L;
    }
}

// ---------------- plain bf16 GEMM (o-branch / epilogue), round-1 ------------
__global__ __launch_bounds__(256) void gemm_bf16(
    const __hip_bfloat16* __restrict__ A, long long sA, int lda,
    const __hip_bfloat16* __restrict__ B, long long sB, int ldb,
    void* __restrict__ D, long long sD, int ldd,
    const __hip_bfloat16* __restrict__ addsrc, long long sAdd, int ldadd,
    const float* __restrict__ bias,
    int K, int relu, int outF32)
{
    __shared__ __hip_bfloat16 As[TILE * LDSS];
    __shared__ __hip_bfloat16 Bs[TILE * LDSS]; // transposed: Bs[n][k]

    int bx = blockIdx.x, by = blockIdx.y, bz = blockIdx.z;
    swz_block(bx, by, bz);

    const int tid  = threadIdx.x;
    const int lane = tid & 63;
    const int wave = tid >> 6;
    const int wm   = (wave >> 1) * 64;
    const int wn   = (wave & 1) * 64;
    const int row0 = by * TILE;
    const int col0 = bx * TILE;
    const int b    = bz;

    const __hip_bfloat16* Ab = A + (size_t)b * sA;
    const __hip_bfloat16* Bb = B + (size_t)b * sB;

    f32x4 acc[4][4];
#pragma unroll
    for (int i = 0; i < 4; ++i)
#pragma unroll
        for (int j = 0; j < 4; ++j) acc[i][j] = (f32x4){0.f, 0.f, 0.f, 0.f};

    const int quad = lane >> 4;
    const int l16  = lane & 15;

    for (int k0 = 0; k0 < K; k0 += BKK) {
        __syncthreads();
#pragma unroll
        for (int it = 0; it < 2; ++it) {
            int task = tid + it * 256;
            int m = task >> 2, kq = task & 3;
            uint4 val = *(const uint4*)(Ab + (size_t)(row0 + m) * lda + k0 + kq * 8);
            *(uint4*)(&As[m * LDSS + kq * 8]) = val;
        }
#pragma unroll
        for (int it = 0; it < 2; ++it) {
            int task = tid + it * 256;
            int kk = task >> 4, n8 = task & 15;
            uint4 val = *(const uint4*)(Bb + (size_t)(k0 + kk) * ldb + col0 + n8 * 8);
            const __hip_bfloat16* v16 = (const __hip_bfloat16*)&val;
#pragma unroll
            for (int u = 0; u < 8; ++u)
                Bs[(n8 * 8 + u) * LDSS + kk] = v16[u];
        }
        __syncthreads();

        bf16x8s afrag[4], bfrag[4];
#pragma unroll
        for (int mt = 0; mt < 4; ++mt)
            afrag[mt] = *(const bf16x8s*)(&As[(wm + mt * 16 + l16) * LDSS + quad * 8]);
#pragma unroll
        for (int nt = 0; nt < 4; ++nt)
            bfrag[nt] = *(const bf16x8s*)(&Bs[(wn + nt * 16 + l16) * LDSS + quad * 8]);
#pragma unroll
        for (int mt = 0; mt < 4; ++mt)
#pragma unroll
            for (int nt = 0; nt < 4; ++nt)
                acc[mt][nt] = __builtin_amdgcn_mfma_f32_16x16x32_bf16(
                    afrag[mt], bfrag[nt], acc[mt][nt], 0, 0, 0);
    }

    __hip_bfloat16* Db16 = (__hip_bfloat16*)D + (size_t)b * sD;
    float*          DbF  = (float*)D + (size_t)b * sD;
    const __hip_bfloat16* Addb = addsrc ? addsrc + (size_t)b * sAdd : nullptr;
#pragma unroll
    for (int mt = 0; mt < 4; ++mt)
#pragma unroll
        for (int nt = 0; nt < 4; ++nt)
#pragma unroll
            for (int r = 0; r < 4; ++r) {
                int m = row0 + wm + mt * 16 + quad * 4 + r;
                int n = col0 + wn + nt * 16 + l16;
                float v = acc[mt][nt][r];
                if (Addb) v += __bfloat162float(Addb[(size_t)m * ldadd + n]);
                if (bias) v += bias[n];
                if (relu && v < 0.f) v = 0.f;
                if (outF32) DbF[(size_t)m * ldd + n] = v;
                else        Db16[(size_t)m * ldd + n] = __float2bfloat16(v);
            }
}

// fp32 -> bf16 converter (n divisible by 4)
__global__ void convert_kernel(const float* __restrict__ src,
                               __hip_bfloat16* __restrict__ dst, int n4)
{
    int i = blockIdx.x * blockDim.x + threadIdx.x;
    if (i >= n4) return;
    float4 v = ((const float4*)src)[i];
    __hip_bfloat16 t0 = __float2bfloat16(v.x), t1 = __float2bfloat16(v.y);
    __hip_bfloat16 t2 = __float2bfloat16(v.z), t3 = __float2bfloat16(v.w);
    ushort4 o = { *(unsigned short*)&t0, *(unsigned short*)&t1,
                  *(unsigned short*)&t2, *(unsigned short*)&t3 };
    ((ushort4*)dst)[i] = o;
}

// fp32 -> hi/lo plane splitter (n divisible by 4)
__global__ void split_kernel(const float* __restrict__ src,
                             __hip_bfloat16* __restrict__ dh,
                             __hip_bfloat16* __restrict__ dl, int n4)
{
    int i = blockIdx.x * blockDim.x + threadIdx.x;
    if (i >= n4) return;
    float4 v = ((const float4*)src)[i];
    ushort4 H, L;
    splitw(v.x, H.x, L.x); splitw(v.y, H.y, L.y);
    splitw(v.z, H.z, L.z); splitw(v.w, H.w, L.w);
    ((ushort4*)dh)[i] = H;
    ((ushort4*)dl)[i] = L;
}

// ---------------- fused segment attention + query-mean (fp32 q/k/v) ---------
__global__ __launch_bounds__(256) void attn_kernel(
    const float* __restrict__ q,
    const float* __restrict__ k,
    const float* __restrict__ v,
    __hip_bfloat16* __restrict__ abar)
{
    __shared__ float qs[8][512], ks[8][512], vs[8][512];
    __shared__ float sc[4][8][8];
    __shared__ float wb[4][8];

    const int tid  = threadIdx.x;
    const int mode = blockIdx.y;
    const int g    = blockIdx.x >> 3;
    const int idx  = blockIdx.x & 7;
    const int rowBase = g * 64;

    for (int t = tid; t < 512; t += 256) {
        int p = t >> 6, c8 = (t & 63) * 8;
        int row = (mode == 0) ? (rowBase + idx * 8 + p) : (rowBase + p * 8 + idx);
        const float* qp = q + (size_t)row * 512 + c8;
        const float* kp = k + (size_t)row * 512 + c8;
        const float* vp = v + (size_t)row * 512 + c8;
        *(float4*)(&qs[p][c8])     = *(const float4*)(qp);
        *(float4*)(&qs[p][c8 + 4]) = *(const float4*)(qp + 4);
        *(float4*)(&ks[p][c8])     = *(const float4*)(kp);
        *(float4*)(&ks[p][c8 + 4]) = *(const float4*)(kp + 4);
        *(float4*)(&vs[p][c8])     = *(const float4*)(vp);
        *(float4*)(&vs[p][c8 + 4]) = *(const float4*)(vp + 4);
    }
    __syncthreads();

    {
        int h = tid >> 6, l = tid & 63;
        int i = l >> 3, j = l & 7;
        const float* qrow = &qs[i][h * 128];
        const float* krow = &ks[j][h * 128];
        float s = 0.f;
#pragma unroll
        for (int d = 0; d < 128; d += 4) {
            float4 qa = *(const float4*)(qrow + d);
            float4 kb = *(const float4*)(krow + d);
            s += qa.x * kb.x + qa.y * kb.y + qa.z * kb.z + qa.w * kb.w;
        }
        sc[h][i][j] = s * 0.08838834764831845f;
    }
    __syncthreads();

    if (tid < 32) {
        int h = tid >> 3, i = tid & 7;
        float mx = -1e30f;
#pragma unroll
        for (int j = 0; j < 8; ++j) mx = fmaxf(mx, sc[h][i][j]);
        float e[8], sum = 0.f;
#pragma unroll
        for (int j = 0; j < 8; ++j) { e[j] = __expf(sc[h][i][j] - mx); sum += e[j]; }
        float inv = 1.f / sum;
#pragma unroll
        for (int j = 0; j < 8; ++j) sc[h][i][j] = e[j] * inv;
    }
    __syncthreads();

    if (tid < 32) {
        int h = tid >> 3, j = tid & 7;
        float s = 0.f;
#pragma unroll
        for (int i = 0; i < 8; ++i) s += sc[h][i][j];
        wb[h][j] = s * 0.125f;
    }
    __syncthreads();

    {
        int orow = g * 16 + mode * 8 + idx;
        for (int c = tid; c < 512; c += 256) {
            int h = c >> 7;
            float o = 0.f;
#pragma unroll
            for (int j = 0; j < 8; ++j) o += wb[h][j] * vs[j][c];
            abar[(size_t)orow * 512 + c] = __float2bfloat16(o);
        }
    }
}

// ---------------------------------------------------------------------------

extern "C" void kernel_launch(void* const* d_in, const int* in_sizes, int n_in,
                              void* d_out, int out_size, void* d_ws, size_t ws_size,
                              hipStream_t stream)
{
    const float* Ao   = (const float*)d_in[0];   // (8,512,512)
    const float* srco = (const float*)d_in[1];   // (4096,1024)
    const float* Ar   = (const float*)d_in[2];   // (8,2048,2048)
    const float* srcr = (const float*)d_in[3];   // (16384,300)
    const float* Wo1  = (const float*)d_in[4];   // (1024,1024)
    const float* Wo2  = (const float*)d_in[5];   // (1024,512)
    const float* Wr1  = (const float*)d_in[6];   // (300,1024)
    const float* Wr2  = (const float*)d_in[7];   // (1024,512)
    const float* Wq   = (const float*)d_in[8];
    const float* bq   = (const float*)d_in[9];
    const float* Wk   = (const float*)d_in[10];
    const float* bk   = (const float*)d_in[11];
    const float* Wv   = (const float*)d_in[12];
    const float* bv   = (const float*)d_in[13];
    const float* Wp   = (const float*)d_in[14];
    const float* bp   = (const float*)d_in[15];
    const float* We   = (const float*)d_in[16];  // (1024,512)
    const float* be   = (const float*)d_in[17];
    float* out = (float*)d_out;                  // (4096,512) fp32

    char* ws = (char*)d_ws;
    // R0 (0, 67.1M):      HR planes -> later qF(+0), kF(+33.55M)
    // R1 (67.1M, 33.5M):  T2Rf fp32 -> later vF
    // R2 (100.7M, 33.5M): U planes, then T2RT planes, then o-branch bf16 pool
    // R3 (134.2M, 33.5M): GR planes
    // R4 (167.8M, 25.2M): XPT planes -> later ABAR (bf16, 4.2M)
    // R5 (193.0M, 6.6M):  transposed weight planes
    // R6 (199.5M, 134.2M): OPTIONAL Ar planes (only if ws_size permits)
    const size_t R0 = 0;
    const size_t R1 = 67108864;
    const size_t R2 = 100663296;
    const size_t R3 = 134217728;
    const size_t R4 = 167772160;
    const size_t R5 = 192937984;
    const size_t R6 = 199491584;

    __hip_bfloat16* HRh = (__hip_bfloat16*)(ws + R0);
    __hip_bfloat16* HRl = HRh + 16777216;            // 16384x1024 each
    float* qF   = (float*)(ws + R0);
    float* kF   = (float*)(ws + R0 + 33554432);
    float* T2Rf = (float*)(ws + R1);                 // 16384x512 fp32
    float* vF   = (float*)(ws + R1);
    __hip_bfloat16* Uh = (__hip_bfloat16*)(ws + R2);
    __hip_bfloat16* Ul = Uh + 6291456;               // 16384x384 each
    __hip_bfloat16* T2RTh = (__hip_bfloat16*)(ws + R2);
    __hip_bfloat16* T2RTl = T2RTh + 8388608;         // 8x512x2048 each
    __hip_bfloat16* GRh = (__hip_bfloat16*)(ws + R3);
    __hip_bfloat16* GRl = GRh + 8388608;             // 16384x512 each
    __hip_bfloat16* XPTh = (__hip_bfloat16*)(ws + R4);
    __hip_bfloat16* XPTl = XPTh + 6291456;           // 8x384x2048 each
    __hip_bfloat16* ABAR = (__hip_bfloat16*)(ws + R4);
    __hip_bfloat16* WPTh = (__hip_bfloat16*)(ws + R5);               // 1024x320
    __hip_bfloat16* WPTl = WPTh + 327680;
    __hip_bfloat16* Wr2Th = (__hip_bfloat16*)(ws + R5 + 1310720);    // 512x1024
    __hip_bfloat16* Wr2Tl = Wr2Th + 524288;
    __hip_bfloat16* WqTh = (__hip_bfloat16*)(ws + R5 + 3407872);     // 512x512
    __hip_bfloat16* WqTl = WqTh + 262144;
    __hip_bfloat16* WkTh = (__hip_bfloat16*)(ws + R5 + 4456448);
    __hip_bfloat16* WkTl = WkTh + 262144;
    __hip_bfloat16* WvTh = (__hip_bfloat16*)(ws + R5 + 5505024);
    __hip_bfloat16* WvTl = WvTh + 262144;
    __hip_bfloat16* Arh = (__hip_bfloat16*)(ws + R6);                // 8x2048x2048
    __hip_bfloat16* Arl = Arh + 33554432;
    const bool haveArPlanes = ws_size >= R6 + 2ull * 67108864ull;    // 333.7MB

    // o-branch bf16 pool at R2 (valid after attn inputs consumed)
    __hip_bfloat16* TO    = (__hip_bfloat16*)(ws + R2 + 0);
    __hip_bfloat16* HO    = (__hip_bfloat16*)(ws + R2 + 8388608);
    __hip_bfloat16* T2O   = (__hip_bfloat16*)(ws + R2 + 16777216);
    __hip_bfloat16* CAT   = (__hip_bfloat16*)(ws + R2 + 20971520);
    __hip_bfloat16* srcoB = (__hip_bfloat16*)(ws + R2 + 29360128);
    __hip_bfloat16* AoB   = (__hip_bfloat16*)(ws + R2 + 37748736);
    __hip_bfloat16* Wo1B  = (__hip_bfloat16*)(ws + R2 + 41943040);
    __hip_bfloat16* Wo2B  = (__hip_bfloat16*)(ws + R2 + 44040192);
    __hip_bfloat16* WeB   = (__hip_bfloat16*)(ws + R2 + 45088768);
    __hip_bfloat16* WpB   = (__hip_bfloat16*)(ws + R2 + 46137344);

    dim3 blk(256);
    auto cvt = [&](const float* s, __hip_bfloat16* d, int n) {
        convert_kernel<<<dim3((n / 4 + 255) / 256), blk, 0, stream>>>(s, d, n / 4);
    };

    // ---- transposes (emit hi/lo planes) ----
    padtrans_split<<<dim3(6, 32, 8), blk, 0, stream>>>(srcr, XPTh, XPTl, 2048, 300, 2048, 384);
    padtrans_split<<<dim3(16, 5, 1), blk, 0, stream>>>(Wr1, WPTh, WPTl, 300, 1024, 320, 1024);
    padtrans_split<<<dim3(8, 16, 1), blk, 0, stream>>>(Wr2, Wr2Th, Wr2Tl, 1024, 512, 1024, 512);
    padtrans_split<<<dim3(8, 8, 1), blk, 0, stream>>>(Wq, WqTh, WqTl, 512, 512, 512, 512);
    padtrans_split<<<dim3(8, 8, 1), blk, 0, stream>>>(Wk, WkTh, WkTl, 512, 512, 512, 512);
    padtrans_split<<<dim3(8, 8, 1), blk, 0, stream>>>(Wv, WvTh, WvTl, 512, 512, 512, 512);

    // ---- r-branch (split precision, planes in memory) ----
    if (haveArPlanes) {
        split_kernel<<<dim3(32768), blk, 0, stream>>>(Ar, Arh, Arl, 8388608);
        // U = Ar@XP + XP -> U planes
        gemm_planes<<<dim3(3, 16, 8), blk, 0, stream>>>(
            Arh, Arl, 2048LL * 2048, 2048, XPTh, XPTl, 384LL * 2048, 2048,
            Uh, Ul, 2048LL * 384, 384,
            nullptr, 0, 0, XPTh, XPTl, 384LL * 2048, 2048,
            nullptr, 2048, 0, 1);
    } else {
        gemm_asplit<<<dim3(3, 16, 8), blk, 0, stream>>>(
            Ar, 2048LL * 2048, 2048, XPTh, XPTl, 384LL * 2048, 2048,
            Uh, Ul, 2048LL * 384, 384,
            nullptr, 0, 0, XPTh, XPTl, 384LL * 2048, 2048,
            2048, 0);
    }
    // HR = relu(U@WP)  (16384x320 @ 320x1024) -> HR planes
    gemm_planes<<<dim3(8, 128, 1), blk, 0, stream>>>(
        Uh, Ul, 0, 384, WPTh, WPTl, 0, 320,
        HRh, HRl, 0, 1024,
        nullptr, 0, 0, nullptr, nullptr, 0, 0,
        nullptr, 320, 1, 1);
    // T2R = HR@Wr2  (16384x1024 @ 1024x512) -> fp32 (addN + transpose src)
    gemm_planes<<<dim3(4, 128, 1), blk, 0, stream>>>(
        HRh, HRl, 0, 1024, Wr2Th, Wr2Tl, 0, 1024,
        T2Rf, nullptr, 0, 512,
        nullptr, 0, 0, nullptr, nullptr, 0, 0,
        nullptr, 1024, 0, 0);
    // T2RT (8,512,2048) planes from T2Rf viewed (8,2048,512)
    padtrans_split<<<dim3(8, 32, 8), blk, 0, stream>>>(T2Rf, T2RTh, T2RTl, 2048, 512, 2048, 512);
    // GR = relu(Ar@T2R + T2R) -> GR planes
    if (haveArPlanes) {
        gemm_planes<<<dim3(4, 16, 8), blk, 0, stream>>>(
            Arh, Arl, 2048LL * 2048, 2048, T2RTh, T2RTl, 512LL * 2048, 2048,
            GRh, GRl, 2048LL * 512, 512,
            T2Rf, 2048LL * 512, 512, nullptr, nullptr, 0, 0,
            nullptr, 2048, 1, 1);
    } else {
        gemm_asplit<<<dim3(4, 16, 8), blk, 0, stream>>>(
            Ar, 2048LL * 2048, 2048, T2RTh, T2RTl, 512LL * 2048, 2048,
            GRh, GRl, 2048LL * 512, 512,
            T2Rf, 2048LL * 512, 512, nullptr, nullptr, 0, 0,
            2048, 1);
    }
    // q/k/v = GR @ W? + b?  (16384x512 @ 512x512) -> fp32
    gemm_planes<<<dim3(4, 128, 1), blk, 0, stream>>>(
        GRh, GRl, 0, 512, WqTh, WqTl, 0, 512,
        qF, nullptr, 0, 512,
        nullptr, 0, 0, nullptr, nullptr, 0, 0,
        bq, 512, 0, 0);
    gemm_planes<<<dim3(4, 128, 1), blk, 0, stream>>>(
        GRh, GRl, 0, 512, WkTh, WkTl, 0, 512,
        kF, nullptr, 0, 512,
        nullptr, 0, 0, nullptr, nullptr, 0, 0,
        bk, 512, 0, 0);
    gemm_planes<<<dim3(4, 128, 1), blk, 0, stream>>>(
        GRh, GRl, 0, 512, WvTh, WvTl, 0, 512,
        vF, nullptr, 0, 512,
        nullptr, 0, 0, nullptr, nullptr, 0, 0,
        bv, 512, 0, 0);
    // fused attention + query-mean -> ABAR bf16 (4096,512); XPT planes dead
    attn_kernel<<<dim3(2048, 2), blk, 0, stream>>>(qF, kF, vF, ABAR);

    // ---- o-branch (bf16) ----
    cvt(srco, srcoB, 4194304);
    cvt(Ao, AoB, 2097152);
    cvt(Wo1, Wo1B, 1048576);
    cvt(Wo2, Wo2B, 524288);
    cvt(We, WeB, 524288);
    cvt(Wp, WpB, 262144);
    // TO = srco @ Wo1  (4096,1024)@(1024,1024)
    gemm_bf16<<<dim3(8, 32, 1), blk, 0, stream>>>(srcoB, 0, 1024, Wo1B, 0, 1024,
        TO, 0, 1024, nullptr, 0, 0, nullptr, 1024, 0, 0);
    // HO = relu(Ao@TO + TO)  batched 8
    gemm_bf16<<<dim3(8, 4, 8), blk, 0, stream>>>(AoB, 512LL * 512, 512, TO, 512LL * 1024, 1024,
        HO, 512LL * 1024, 1024, TO, 512LL * 1024, 1024, nullptr, 512, 1, 0);
    // T2O = HO @ Wo2  (4096,1024)@(1024,512)
    gemm_bf16<<<dim3(4, 32, 1), blk, 0, stream>>>(HO, 0, 1024, Wo2B, 0, 512,
        T2O, 0, 512, nullptr, 0, 0, nullptr, 1024, 0, 0);
    // g_o = relu(Ao@T2O + T2O) -> CAT right half
    gemm_bf16<<<dim3(4, 4, 8), blk, 0, stream>>>(AoB, 512LL * 512, 512, T2O, 512LL * 512, 512,
        (void*)(CAT + 512), 512LL * 1024, 1024, T2O, 512LL * 512, 512, nullptr, 512, 1, 0);
    // P = ABAR @ Wp + bp -> CAT left half
    gemm_bf16<<<dim3(4, 32, 1), blk, 0, stream>>>(ABAR, 0, 512, WpB, 0, 512,
        CAT, 0, 1024, nullptr, 0, 0, bp, 512, 0, 0);
    // out = CAT @ We + be  -> fp32
    gemm_bf16<<<dim3(4, 32, 1), blk, 0, stream>>>(CAT, 0, 1024, WeB, 0, 512,
        out, 0, 512, nullptr, 0, 0, be, 1024, 0, 1);
}

// Round 7
// 1014.705 us; speedup vs baseline: 1.1158x; 1.1158x over previous
//
#include <hip/hip_runtime.h>
#include <hip/hip_bf16.h>

// ---------------------------------------------------------------------------
// B=8, NT=32, NO=8, C=512, VD=1024, RD=300; No=512, Nr=2048.
// r-chain: split-bf16 (hi/lo planes) MFMA, ~fp32 accurate, planes in memory
// end-to-end (incl. one-shot Ar pre-split). Round-7:
//  - q/k/v fused into ONE gemm_planes call (16384x1536x512): concatenated
//    transposed weight planes (exactly fill R5) + concat bias; fp32 QKV
//    buffer spans R0+R1 (ld=1536); attn takes a row-stride param.
//  - gemm_bf16t: async counted-vmcnt + XOR-swizzle structure (as gemm_planes)
//    for single-plane bf16 with PRE-TRANSPOSED B — used for the 4 weight-B
//    o-branch GEMMs (TO, T2O, P, out). Weights get padtrans_bf16.
//  - Ar GEMMs unchanged (at ~82% of the 128^2/2-phase structural ceiling).
// ---------------------------------------------------------------------------

typedef __attribute__((ext_vector_type(4))) float f32x4;
typedef __attribute__((ext_vector_type(8))) short bf16x8s;

#define TILE 128
#define BKK 32
#define LDSS 40  // padded stride for the sync-staged kernels (asplit/bf16)
#define LDSL 32  // linear stride for DMA-staged kernels

#if __has_builtin(__builtin_amdgcn_global_load_lds)
#define HAVE_GLL 1
#else
#define HAVE_GLL 0
#endif

__device__ inline void gll16(const __hip_bfloat16* g, __hip_bfloat16* l) {
#if HAVE_GLL
    __builtin_amdgcn_global_load_lds(
        (const __attribute__((address_space(1))) void*)g,
        (__attribute__((address_space(3))) void*)l,
        16, 0, 0);
#endif
}

__device__ inline void split2(float a, float b, unsigned& h, unsigned& l) {
    __hip_bfloat16 ha = __float2bfloat16(a), hb = __float2bfloat16(b);
    float ra = __bfloat162float(ha), rb = __bfloat162float(hb);
    __hip_bfloat16 la = __float2bfloat16(a - ra), lb = __float2bfloat16(b - rb);
    unsigned short uha = *(unsigned short*)&ha, uhb = *(unsigned short*)&hb;
    unsigned short ula = *(unsigned short*)&la, ulb = *(unsigned short*)&lb;
    h = (unsigned)uha | ((unsigned)uhb << 16);
    l = (unsigned)ula | ((unsigned)ulb << 16);
}

__device__ inline void splitw(float v, unsigned short& h, unsigned short& l) {
    __hip_bfloat16 hb = __float2bfloat16(v);
    __hip_bfloat16 lb = __float2bfloat16(v - __bfloat162float(hb));
    h = *(unsigned short*)&hb;
    l = *(unsigned short*)&lb;
}

// XCD-aware bijective block swizzle (all grids here have nwg % 8 == 0).
__device__ inline void swz_block(int& bx, int& by, int& bz) {
    int gx = gridDim.x, gy = gridDim.y;
    int nwg = gx * gy * gridDim.z;
    int flat = bx + gx * (by + gy * bz);
    int cpx = nwg >> 3;
    int w = (flat & 7) * cpx + (flat >> 3);
    bx = w % gx;
    int t = w / gx;
    by = t % gy;
    bz = t / gy;
}

// ---------------- GEMM: both A and B pre-split planes, counted-vmcnt --------
__global__ __launch_bounds__(256) void gemm_planes(
    const __hip_bfloat16* __restrict__ Aph, const __hip_bfloat16* __restrict__ Apl,
    long long sA, int lda,
    const __hip_bfloat16* __restrict__ BTh, const __hip_bfloat16* __restrict__ BTl,
    long long sBT, int ldbt,
    void* __restrict__ D, __hip_bfloat16* __restrict__ Dl_, long long sD, int ldd,
    const float* __restrict__ addN, long long sAddN, int ldaddN,
    const __hip_bfloat16* __restrict__ addTh, const __hip_bfloat16* __restrict__ addTl,
    long long sAddT, int ldaddT,
    const float* __restrict__ bias,
    int K, int relu, int outMode)
{
    __shared__ __hip_bfloat16 AhB[2][TILE * LDSL], AlB[2][TILE * LDSL];
    __shared__ __hip_bfloat16 BhB[2][TILE * LDSL], BlB[2][TILE * LDSL];

    int bx = blockIdx.x, by = blockIdx.y, bz = blockIdx.z;
    swz_block(bx, by, bz);

    const int tid  = threadIdx.x;
    const int lane = tid & 63;
    const int wave = tid >> 6;
    const int wm   = (wave >> 1) * 64;
    const int wn   = (wave & 1) * 64;
    const int row0 = by * TILE;
    const int col0 = bx * TILE;
    const int b    = bz;

    const __hip_bfloat16* Abh = Aph + (size_t)b * sA;
    const __hip_bfloat16* Abl = Apl + (size_t)b * sA;
    const __hip_bfloat16* Bbh = BTh + (size_t)b * sBT;
    const __hip_bfloat16* Bbl = BTl + (size_t)b * sBT;

    f32x4 acc[4][4];
#pragma unroll
    for (int i = 0; i < 4; ++i)
#pragma unroll
        for (int j = 0; j < 4; ++j) acc[i][j] = (f32x4){0.f, 0.f, 0.f, 0.f};

    const int quad = lane >> 4;
    const int l16  = lane & 15;

    const int m0  = wave * 16 + (lane >> 2);
    const int m1  = (wave + 4) * 16 + (lane >> 2);
    const int sl  = lane & 3;
    const int kq0 = sl ^ ((m0 >> 1) & 3);
    const int kq1 = sl ^ ((m1 >> 1) & 3);
    const size_t gA0 = (size_t)(row0 + m0) * lda + kq0 * 8;
    const size_t gA1 = (size_t)(row0 + m1) * lda + kq1 * 8;
    const size_t gB0 = (size_t)(col0 + m0) * ldbt + kq0 * 8;
    const size_t gB1 = (size_t)(col0 + m1) * ldbt + kq1 * 8;
    const int ldsc0 = wave * 512;
    const int ldsc1 = (wave + 4) * 512;

#if HAVE_GLL
#define STAGE(buf, kk) do { \
    gll16(Abh + gA0 + (kk), &AhB[buf][ldsc0]); \
    gll16(Abh + gA1 + (kk), &AhB[buf][ldsc1]); \
    gll16(Abl + gA0 + (kk), &AlB[buf][ldsc0]); \
    gll16(Abl + gA1 + (kk), &AlB[buf][ldsc1]); \
    gll16(Bbh + gB0 + (kk), &BhB[buf][ldsc0]); \
    gll16(Bbh + gB1 + (kk), &BhB[buf][ldsc1]); \
    gll16(Bbl + gB0 + (kk), &BlB[buf][ldsc0]); \
    gll16(Bbl + gB1 + (kk), &BlB[buf][ldsc1]); \
} while (0)
#define WAITVM8() asm volatile("s_waitcnt vmcnt(8)" ::: "memory")
#define WAITVM0() asm volatile("s_waitcnt vmcnt(0)" ::: "memory")
#else
#define STAGE(buf, kk) do { \
    *(uint4*)(&AhB[buf][m0 * LDSL + sl * 8]) = *(const uint4*)(Abh + gA0 + (kk)); \
    *(uint4*)(&AhB[buf][m1 * LDSL + sl * 8]) = *(const uint4*)(Abh + gA1 + (kk)); \
    *(uint4*)(&AlB[buf][m0 * LDSL + sl * 8]) = *(const uint4*)(Abl + gA0 + (kk)); \
    *(uint4*)(&AlB[buf][m1 * LDSL + sl * 8]) = *(const uint4*)(Abl + gA1 + (kk)); \
    *(uint4*)(&BhB[buf][m0 * LDSL + sl * 8]) = *(const uint4*)(Bbh + gB0 + (kk)); \
    *(uint4*)(&BhB[buf][m1 * LDSL + sl * 8]) = *(const uint4*)(Bbh + gB1 + (kk)); \
    *(uint4*)(&BlB[buf][m0 * LDSL + sl * 8]) = *(const uint4*)(Bbl + gB0 + (kk)); \
    *(uint4*)(&BlB[buf][m1 * LDSL + sl * 8]) = *(const uint4*)(Bbl + gB1 + (kk)); \
} while (0)
#define WAITVM8() asm volatile("" ::: "memory")
#define WAITVM0() asm volatile("" ::: "memory")
#endif

    const int nt = K / BKK;
    int cur = 0;

    STAGE(0, 0);
    STAGE(1, BKK);

    for (int t = 0; t < nt; ++t) {
        if (t + 1 < nt) { WAITVM8(); } else { WAITVM0(); }
        __builtin_amdgcn_s_barrier();

        const __hip_bfloat16* Ah = AhB[cur];
        const __hip_bfloat16* Al = AlB[cur];
        const __hip_bfloat16* Bh = BhB[cur];
        const __hip_bfloat16* Bl = BlB[cur];

        bf16x8s bhf[4], blf[4];
#pragma unroll
        for (int nt2 = 0; nt2 < 4; ++nt2) {
            int r = wn + nt2 * 16 + l16;
            int ss = (quad ^ ((r >> 1) & 3)) * 8;
            bhf[nt2] = *(const bf16x8s*)(&Bh[r * LDSL + ss]);
            blf[nt2] = *(const bf16x8s*)(&Bl[r * LDSL + ss]);
        }
#pragma unroll
        for (int mt = 0; mt < 4; ++mt) {
            int r = wm + mt * 16 + l16;
            int ss = (quad ^ ((r >> 1) & 3)) * 8;
            bf16x8s ahf = *(const bf16x8s*)(&Ah[r * LDSL + ss]);
            bf16x8s alf = *(const bf16x8s*)(&Al[r * LDSL + ss]);
#pragma unroll
            for (int nt2 = 0; nt2 < 4; ++nt2) {
                acc[mt][nt2] = __builtin_amdgcn_mfma_f32_16x16x32_bf16(ahf, bhf[nt2], acc[mt][nt2], 0, 0, 0);
                acc[mt][nt2] = __builtin_amdgcn_mfma_f32_16x16x32_bf16(ahf, blf[nt2], acc[mt][nt2], 0, 0, 0);
                acc[mt][nt2] = __builtin_amdgcn_mfma_f32_16x16x32_bf16(alf, bhf[nt2], acc[mt][nt2], 0, 0, 0);
            }
        }

        __builtin_amdgcn_s_barrier();
        if (t + 2 < nt) STAGE(cur, (t + 2) * BKK);
        cur ^= 1;
    }
#undef STAGE
#undef WAITVM8
#undef WAITVM0

    float* DbF = (float*)D + (size_t)b * sD;
    __hip_bfloat16* Dhb = (__hip_bfloat16*)D + (size_t)b * sD;
    __hip_bfloat16* Dlb = Dl_ ? Dl_ + (size_t)b * sD : nullptr;
    const float* AddN = addN ? addN + (size_t)b * sAddN : nullptr;
    const __hip_bfloat16* ATh = addTh ? addTh + (size_t)b * sAddT : nullptr;
    const __hip_bfloat16* ATl = addTl ? addTl + (size_t)b * sAddT : nullptr;
#pragma unroll
    for (int mt = 0; mt < 4; ++mt)
#pragma unroll
        for (int nt2 = 0; nt2 < 4; ++nt2)
#pragma unroll
            for (int r = 0; r < 4; ++r) {
                int m = row0 + wm + mt * 16 + quad * 4 + r;
                int n = col0 + wn + nt2 * 16 + l16;
                float v = acc[mt][nt2][r];
                if (AddN) v += AddN[(size_t)m * ldaddN + n];
                if (ATh) v += __bfloat162float(ATh[(size_t)n * ldaddT + m])
                            + __bfloat162float(ATl[(size_t)n * ldaddT + m]);
                if (bias) v += bias[n];
                if (relu && v < 0.f) v = 0.f;
                if (outMode == 0) {
                    DbF[(size_t)m * ldd + n] = v;
                } else {
                    unsigned short hh, ll;
                    splitw(v, hh, ll);
                    size_t o = (size_t)m * ldd + n;
                    *(unsigned short*)&Dhb[o] = hh;
                    *(unsigned short*)&Dlb[o] = ll;
                }
            }
}

// ---------------- GEMM: plain bf16, B pre-transposed, counted-vmcnt ---------
// D = A@B + bias; A:(M,K) bf16, BT:(N,K) bf16. outF32: fp32 D else bf16.
__global__ __launch_bounds__(256) void gemm_bf16t(
    const __hip_bfloat16* __restrict__ A, int lda,
    const __hip_bfloat16* __restrict__ BT, int ldbt,
    void* __restrict__ D, int ldd,
    const float* __restrict__ bias,
    int K, int outF32)
{
    __shared__ __hip_bfloat16 AsB[2][TILE * LDSL];
    __shared__ __hip_bfloat16 BsB[2][TILE * LDSL];

    int bx = blockIdx.x, by = blockIdx.y, bz = blockIdx.z;
    swz_block(bx, by, bz);

    const int tid  = threadIdx.x;
    const int lane = tid & 63;
    const int wave = tid >> 6;
    const int wm   = (wave >> 1) * 64;
    const int wn   = (wave & 1) * 64;
    const int row0 = by * TILE;
    const int col0 = bx * TILE;

    f32x4 acc[4][4];
#pragma unroll
    for (int i = 0; i < 4; ++i)
#pragma unroll
        for (int j = 0; j < 4; ++j) acc[i][j] = (f32x4){0.f, 0.f, 0.f, 0.f};

    const int quad = lane >> 4;
    const int l16  = lane & 15;

    const int m0  = wave * 16 + (lane >> 2);
    const int m1  = (wave + 4) * 16 + (lane >> 2);
    const int sl  = lane & 3;
    const int kq0 = sl ^ ((m0 >> 1) & 3);
    const int kq1 = sl ^ ((m1 >> 1) & 3);
    const size_t gA0 = (size_t)(row0 + m0) * lda + kq0 * 8;
    const size_t gA1 = (size_t)(row0 + m1) * lda + kq1 * 8;
    const size_t gB0 = (size_t)(col0 + m0) * ldbt + kq0 * 8;
    const size_t gB1 = (size_t)(col0 + m1) * ldbt + kq1 * 8;
    const int ldsc0 = wave * 512;
    const int ldsc1 = (wave + 4) * 512;

#if HAVE_GLL
#define STAGE1(buf, kk) do { \
    gll16(A + gA0 + (kk), &AsB[buf][ldsc0]); \
    gll16(A + gA1 + (kk), &AsB[buf][ldsc1]); \
    gll16(BT + gB0 + (kk), &BsB[buf][ldsc0]); \
    gll16(BT + gB1 + (kk), &BsB[buf][ldsc1]); \
} while (0)
#define WAITVM4() asm volatile("s_waitcnt vmcnt(4)" ::: "memory")
#define WAITVM0() asm volatile("s_waitcnt vmcnt(0)" ::: "memory")
#else
#define STAGE1(buf, kk) do { \
    *(uint4*)(&AsB[buf][m0 * LDSL + sl * 8]) = *(const uint4*)(A + gA0 + (kk)); \
    *(uint4*)(&AsB[buf][m1 * LDSL + sl * 8]) = *(const uint4*)(A + gA1 + (kk)); \
    *(uint4*)(&BsB[buf][m0 * LDSL + sl * 8]) = *(const uint4*)(BT + gB0 + (kk)); \
    *(uint4*)(&BsB[buf][m1 * LDSL + sl * 8]) = *(const uint4*)(BT + gB1 + (kk)); \
} while (0)
#define WAITVM4() asm volatile("" ::: "memory")
#define WAITVM0() asm volatile("" ::: "memory")
#endif

    const int nt = K / BKK;
    int cur = 0;

    STAGE1(0, 0);
    STAGE1(1, BKK);

    for (int t = 0; t < nt; ++t) {
        if (t + 1 < nt) { WAITVM4(); } else { WAITVM0(); }
        __builtin_amdgcn_s_barrier();

        const __hip_bfloat16* As = AsB[cur];
        const __hip_bfloat16* Bs = BsB[cur];

        bf16x8s bfrag[4];
#pragma unroll
        for (int nt2 = 0; nt2 < 4; ++nt2) {
            int r = wn + nt2 * 16 + l16;
            int ss = (quad ^ ((r >> 1) & 3)) * 8;
            bfrag[nt2] = *(const bf16x8s*)(&Bs[r * LDSL + ss]);
        }
#pragma unroll
        for (int mt = 0; mt < 4; ++mt) {
            int r = wm + mt * 16 + l16;
            int ss = (quad ^ ((r >> 1) & 3)) * 8;
            bf16x8s afrag = *(const bf16x8s*)(&As[r * LDSL + ss]);
#pragma unroll
            for (int nt2 = 0; nt2 < 4; ++nt2)
                acc[mt][nt2] = __builtin_amdgcn_mfma_f32_16x16x32_bf16(
                    afrag, bfrag[nt2], acc[mt][nt2], 0, 0, 0);
        }

        __builtin_amdgcn_s_barrier();
        if (t + 2 < nt) STAGE1(cur, (t + 2) * BKK);
        cur ^= 1;
    }
#undef STAGE1
#undef WAITVM4
#undef WAITVM0

    float* DbF = (float*)D;
    __hip_bfloat16* Db16 = (__hip_bfloat16*)D;
#pragma unroll
    for (int mt = 0; mt < 4; ++mt)
#pragma unroll
        for (int nt2 = 0; nt2 < 4; ++nt2)
#pragma unroll
            for (int r = 0; r < 4; ++r) {
                int m = row0 + wm + mt * 16 + quad * 4 + r;
                int n = col0 + wn + nt2 * 16 + l16;
                float v = acc[mt][nt2][r];
                if (bias) v += bias[n];
                if (outF32) DbF[(size_t)m * ldd + n] = v;
                else        Db16[(size_t)m * ldd + n] = __float2bfloat16(v);
            }
}

// ---------------- GEMM: A fp32 (in-loop split), B planes (fallback) ---------
__global__ __launch_bounds__(256) void gemm_asplit(
    const float* __restrict__ A, long long sA, int lda,
    const __hip_bfloat16* __restrict__ BTh, const __hip_bfloat16* __restrict__ BTl,
    long long sBT, int ldbt,
    __hip_bfloat16* __restrict__ Dh_, __hip_bfloat16* __restrict__ Dl_,
    long long sD, int ldd,
    const float* __restrict__ addN, long long sAddN, int ldaddN,
    const __hip_bfloat16* __restrict__ addTh, const __hip_bfloat16* __restrict__ addTl,
    long long sAddT, int ldaddT,
    int K, int relu)
{
    __shared__ __hip_bfloat16 Ah[TILE * LDSS], Al[TILE * LDSS];
    __shared__ __hip_bfloat16 Bh[TILE * LDSS], Bl[TILE * LDSS];

    const int tid  = threadIdx.x;
    const int lane = tid & 63;
    const int wave = tid >> 6;
    const int wm   = (wave >> 1) * 64;
    const int wn   = (wave & 1) * 64;
    const int row0 = blockIdx.y * TILE;
    const int col0 = blockIdx.x * TILE;
    const int b    = blockIdx.z;

    const float* Ab = A + (size_t)b * sA;
    const __hip_bfloat16* Bbh = BTh + (size_t)b * sBT;
    const __hip_bfloat16* Bbl = BTl + (size_t)b * sBT;

    f32x4 acc[4][4];
#pragma unroll
    for (int i = 0; i < 4; ++i)
#pragma unroll
        for (int j = 0; j < 4; ++j) acc[i][j] = (f32x4){0.f, 0.f, 0.f, 0.f};

    const int quad = lane >> 4;
    const int l16  = lane & 15;

    for (int k0 = 0; k0 < K; k0 += BKK) {
        __syncthreads();
#pragma unroll
        for (int it = 0; it < 2; ++it) {
            int task = tid + it * 256;
            int m = task >> 2, kq = task & 3;
            const float* ap = Ab + (size_t)(row0 + m) * lda + k0 + kq * 8;
            float4 v0 = *(const float4*)ap;
            float4 v1 = *(const float4*)(ap + 4);
            uint4 H, L;
            split2(v0.x, v0.y, H.x, L.x); split2(v0.z, v0.w, H.y, L.y);
            split2(v1.x, v1.y, H.z, L.z); split2(v1.z, v1.w, H.w, L.w);
            *(uint4*)(&Ah[m * LDSS + kq * 8]) = H;
            *(uint4*)(&Al[m * LDSS + kq * 8]) = L;
        }
#pragma unroll
        for (int it = 0; it < 2; ++it) {
            int task = tid + it * 256;
            int n = task >> 2, kq = task & 3;
            size_t off = (size_t)(col0 + n) * ldbt + k0 + kq * 8;
            *(uint4*)(&Bh[n * LDSS + kq * 8]) = *(const uint4*)(Bbh + off);
            *(uint4*)(&Bl[n * LDSS + kq * 8]) = *(const uint4*)(Bbl + off);
        }
        __syncthreads();

        bf16x8s ah[4], al[4], bh[4], bl[4];
#pragma unroll
        for (int mt = 0; mt < 4; ++mt) {
            int r = (wm + mt * 16 + l16) * LDSS + quad * 8;
            ah[mt] = *(const bf16x8s*)(&Ah[r]);
            al[mt] = *(const bf16x8s*)(&Al[r]);
        }
#pragma unroll
        for (int nt = 0; nt < 4; ++nt) {
            int r = (wn + nt * 16 + l16) * LDSS + quad * 8;
            bh[nt] = *(const bf16x8s*)(&Bh[r]);
            bl[nt] = *(const bf16x8s*)(&Bl[r]);
        }
#pragma unroll
        for (int mt = 0; mt < 4; ++mt)
#pragma unroll
            for (int nt = 0; nt < 4; ++nt) {
                acc[mt][nt] = __builtin_amdgcn_mfma_f32_16x16x32_bf16(ah[mt], bh[nt], acc[mt][nt], 0, 0, 0);
                acc[mt][nt] = __builtin_amdgcn_mfma_f32_16x16x32_bf16(ah[mt], bl[nt], acc[mt][nt], 0, 0, 0);
                acc[mt][nt] = __builtin_amdgcn_mfma_f32_16x16x32_bf16(al[mt], bh[nt], acc[mt][nt], 0, 0, 0);
            }
    }

    __hip_bfloat16* Dhb = Dh_ + (size_t)b * sD;
    __hip_bfloat16* Dlb = Dl_ + (size_t)b * sD;
    const float* AddN = addN ? addN + (size_t)b * sAddN : nullptr;
    const __hip_bfloat16* ATh = addTh ? addTh + (size_t)b * sAddT : nullptr;
    const __hip_bfloat16* ATl = addTl ? addTl + (size_t)b * sAddT : nullptr;
#pragma unroll
    for (int mt = 0; mt < 4; ++mt)
#pragma unroll
        for (int nt = 0; nt < 4; ++nt)
#pragma unroll
            for (int r = 0; r < 4; ++r) {
                int m = row0 + wm + mt * 16 + quad * 4 + r;
                int n = col0 + wn + nt * 16 + l16;
                float v = acc[mt][nt][r];
                if (AddN) v += AddN[(size_t)m * ldaddN + n];
                if (ATh) v += __bfloat162float(ATh[(size_t)n * ldaddT + m])
                            + __bfloat162float(ATl[(size_t)n * ldaddT + m]);
                if (relu && v < 0.f) v = 0.f;
                unsigned short hh, ll;
                splitw(v, hh, ll);
                size_t o = (size_t)m * ldd + n;
                *(unsigned short*)&Dhb[o] = hh;
                *(unsigned short*)&Dlb[o] = ll;
            }
}

// ---------------- tiled fp32 transpose with zero-pad -> hi/lo planes --------
__global__ __launch_bounds__(256) void padtrans_split(
    const float* __restrict__ src,
    __hip_bfloat16* __restrict__ dsth, __hip_bfloat16* __restrict__ dstl,
    int R, int C, int Rp, int Cp)
{
    __shared__ float T[64][65];
    const int t = threadIdx.x;
    const int tr = t >> 4, tc = t & 15;
    const int c0 = blockIdx.x * 64, r0 = blockIdx.y * 64;
    const size_t bat = blockIdx.z;
    const float* sb = src + bat * (size_t)R * C;
    __hip_bfloat16* dhb = dsth + bat * (size_t)Cp * Rp;
    __hip_bfloat16* dlb = dstl + bat * (size_t)Cp * Rp;

#pragma unroll
    for (int i = 0; i < 4; ++i) {
        int rr = tr + i * 16;
        int gr = r0 + rr;
        float v0 = 0.f, v1 = 0.f, v2 = 0.f, v3 = 0.f;
        if (gr < R) {
            int c = c0 + tc * 4;
            const float* s = sb + (size_t)gr * C + c;
            if (c + 0 < C) v0 = s[0];
            if (c + 1 < C) v1 = s[1];
            if (c + 2 < C) v2 = s[2];
            if (c + 3 < C) v3 = s[3];
        }
        T[rr][tc * 4 + 0] = v0; T[rr][tc * 4 + 1] = v1;
        T[rr][tc * 4 + 2] = v2; T[rr][tc * 4 + 3] = v3;
    }
    __syncthreads();
#pragma unroll
    for (int i = 0; i < 4; ++i) {
        int cc = tr + i * 16;
        float4 v = { T[tc * 4 + 0][cc], T[tc * 4 + 1][cc],
                     T[tc * 4 + 2][cc], T[tc * 4 + 3][cc] };
        ushort4 H, L;
        splitw(v.x, H.x, L.x); splitw(v.y, H.y, L.y);
        splitw(v.z, H.z, L.z); splitw(v.w, H.w, L.w);
        size_t off = (size_t)(c0 + cc) * Rp + r0 + tc * 4;
        *(ushort4*)(dhb + off) = H;
        *(ushort4*)(dlb + off) = L;
    }
}

// ---------------- tiled fp32 transpose -> single bf16 (weights) -------------
__global__ __launch_bounds__(256) void padtrans_bf16(
    const float* __restrict__ src, __hip_bfloat16* __restrict__ dst,
    int R, int C, int Rp, int Cp)
{
    __shared__ float T[64][65];
    const int t = threadIdx.x;
    const int tr = t >> 4, tc = t & 15;
    const int c0 = blockIdx.x * 64, r0 = blockIdx.y * 64;

#pragma unroll
    for (int i = 0; i < 4; ++i) {
        int rr = tr + i * 16;
        int gr = r0 + rr;
        float v0 = 0.f, v1 = 0.f, v2 = 0.f, v3 = 0.f;
        if (gr < R) {
            int c = c0 + tc * 4;
            const float* s = src + (size_t)gr * C + c;
            if (c + 0 < C) v0 = s[0];
            if (c + 1 < C) v1 = s[1];
            if (c + 2 < C) v2 = s[2];
            if (c + 3 < C) v3 = s[3];
        }
        T[rr][tc * 4 + 0] = v0; T[rr][tc * 4 + 1] = v1;
        T[rr][tc * 4 + 2] = v2; T[rr][tc * 4 + 3] = v3;
    }
    __syncthreads();
#pragma unroll
    for (int i = 0; i < 4; ++i) {
        int cc = tr + i * 16;
        __hip_bfloat16 b0 = __float2bfloat16(T[tc * 4 + 0][cc]);
        __hip_bfloat16 b1 = __float2bfloat16(T[tc * 4 + 1][cc]);
        __hip_bfloat16 b2 = __float2bfloat16(T[tc * 4 + 2][cc]);
        __hip_bfloat16 b3 = __float2bfloat16(T[tc * 4 + 3][cc]);
        ushort4 o = { *(unsigned short*)&b0, *(unsigned short*)&b1,
                      *(unsigned short*)&b2, *(unsigned short*)&b3 };
        *(ushort4*)(dst + (size_t)(c0 + cc) * Rp + r0 + tc * 4) = o;
    }
}

// ---------------- plain bf16 GEMM (HO / g_o), round-1 structure -------------
__global__ __launch_bounds__(256) void gemm_bf16(
    const __hip_bfloat16* __restrict__ A, long long sA, int lda,
    const __hip_bfloat16* __restrict__ B, long long sB, int ldb,
    void* __restrict__ D, long long sD, int ldd,
    const __hip_bfloat16* __restrict__ addsrc, long long sAdd, int ldadd,
    const float* __restrict__ bias,
    int K, int relu, int outF32)
{
    __shared__ __hip_bfloat16 As[TILE * LDSS];
    __shared__ __hip_bfloat16 Bs[TILE * LDSS]; // transposed: Bs[n][k]

    int bx = blockIdx.x, by = blockIdx.y, bz = blockIdx.z;
    swz_block(bx, by, bz);

    const int tid  = threadIdx.x;
    const int lane = tid & 63;
    const int wave = tid >> 6;
    const int wm   = (wave >> 1) * 64;
    const int wn   = (wave & 1) * 64;
    const int row0 = by * TILE;
    const int col0 = bx * TILE;
    const int b    = bz;

    const __hip_bfloat16* Ab = A + (size_t)b * sA;
    const __hip_bfloat16* Bb = B + (size_t)b * sB;

    f32x4 acc[4][4];
#pragma unroll
    for (int i = 0; i < 4; ++i)
#pragma unroll
        for (int j = 0; j < 4; ++j) acc[i][j] = (f32x4){0.f, 0.f, 0.f, 0.f};

    const int quad = lane >> 4;
    const int l16  = lane & 15;

    for (int k0 = 0; k0 < K; k0 += BKK) {
        __syncthreads();
#pragma unroll
        for (int it = 0; it < 2; ++it) {
            int task = tid + it * 256;
            int m = task >> 2, kq = task & 3;
            uint4 val = *(const uint4*)(Ab + (size_t)(row0 + m) * lda + k0 + kq * 8);
            *(uint4*)(&As[m * LDSS + kq * 8]) = val;
        }
#pragma unroll
        for (int it = 0; it < 2; ++it) {
            int task = tid + it * 256;
            int kk = task >> 4, n8 = task & 15;
            uint4 val = *(const uint4*)(Bb + (size_t)(k0 + kk) * ldb + col0 + n8 * 8);
            const __hip_bfloat16* v16 = (const __hip_bfloat16*)&val;
#pragma unroll
            for (int u = 0; u < 8; ++u)
                Bs[(n8 * 8 + u) * LDSS + kk] = v16[u];
        }
        __syncthreads();

        bf16x8s afrag[4], bfrag[4];
#pragma unroll
        for (int mt = 0; mt < 4; ++mt)
            afrag[mt] = *(const bf16x8s*)(&As[(wm + mt * 16 + l16) * LDSS + quad * 8]);
#pragma unroll
        for (int nt = 0; nt < 4; ++nt)
            bfrag[nt] = *(const bf16x8s*)(&Bs[(wn + nt * 16 + l16) * LDSS + quad * 8]);
#pragma unroll
        for (int mt = 0; mt < 4; ++mt)
#pragma unroll
            for (int nt = 0; nt < 4; ++nt)
                acc[mt][nt] = __builtin_amdgcn_mfma_f32_16x16x32_bf16(
                    afrag[mt], bfrag[nt], acc[mt][nt], 0, 0, 0);
    }

    __hip_bfloat16* Db16 = (__hip_bfloat16*)D + (size_t)b * sD;
    float*          DbF  = (float*)D + (size_t)b * sD;
    const __hip_bfloat16* Addb = addsrc ? addsrc + (size_t)b * sAdd : nullptr;
#pragma unroll
    for (int mt = 0; mt < 4; ++mt)
#pragma unroll
        for (int nt = 0; nt < 4; ++nt)
#pragma unroll
            for (int r = 0; r < 4; ++r) {
                int m = row0 + wm + mt * 16 + quad * 4 + r;
                int n = col0 + wn + nt * 16 + l16;
                float v = acc[mt][nt][r];
                if (Addb) v += __bfloat162float(Addb[(size_t)m * ldadd + n]);
                if (bias) v += bias[n];
                if (relu && v < 0.f) v = 0.f;
                if (outF32) DbF[(size_t)m * ldd + n] = v;
                else        Db16[(size_t)m * ldd + n] = __float2bfloat16(v);
            }
}

// fp32 -> bf16 converter (n divisible by 4)
__global__ void convert_kernel(const float* __restrict__ src,
                               __hip_bfloat16* __restrict__ dst, int n4)
{
    int i = blockIdx.x * blockDim.x + threadIdx.x;
    if (i >= n4) return;
    float4 v = ((const float4*)src)[i];
    __hip_bfloat16 t0 = __float2bfloat16(v.x), t1 = __float2bfloat16(v.y);
    __hip_bfloat16 t2 = __float2bfloat16(v.z), t3 = __float2bfloat16(v.w);
    ushort4 o = { *(unsigned short*)&t0, *(unsigned short*)&t1,
                  *(unsigned short*)&t2, *(unsigned short*)&t3 };
    ((ushort4*)dst)[i] = o;
}

// fp32 -> hi/lo plane splitter (n divisible by 4)
__global__ void split_kernel(const float* __restrict__ src,
                             __hip_bfloat16* __restrict__ dh,
                             __hip_bfloat16* __restrict__ dl, int n4)
{
    int i = blockIdx.x * blockDim.x + threadIdx.x;
    if (i >= n4) return;
    float4 v = ((const float4*)src)[i];
    ushort4 H, L;
    splitw(v.x, H.x, L.x); splitw(v.y, H.y, L.y);
    splitw(v.z, H.z, L.z); splitw(v.w, H.w, L.w);
    ((ushort4*)dh)[i] = H;
    ((ushort4*)dl)[i] = L;
}

// concat three 512-float biases -> 1536
__global__ void bcat_kernel(const float* __restrict__ b0,
                            const float* __restrict__ b1,
                            const float* __restrict__ b2,
                            float* __restrict__ dst)
{
    int i = blockIdx.x * blockDim.x + threadIdx.x;
    if (i >= 1536) return;
    float v = (i < 512) ? b0[i] : (i < 1024) ? b1[i - 512] : b2[i - 1024];
    dst[i] = v;
}

// ---------------- fused segment attention + query-mean (fp32 q/k/v) ---------
__global__ __launch_bounds__(256) void attn_kernel(
    const float* __restrict__ q,
    const float* __restrict__ k,
    const float* __restrict__ v,
    int ld,
    __hip_bfloat16* __restrict__ abar)
{
    __shared__ float qs[8][512], ks[8][512], vs[8][512];
    __shared__ float sc[4][8][8];
    __shared__ float wb[4][8];

    const int tid  = threadIdx.x;
    const int mode = blockIdx.y;
    const int g    = blockIdx.x >> 3;
    const int idx  = blockIdx.x & 7;
    const int rowBase = g * 64;

    for (int t = tid; t < 512; t += 256) {
        int p = t >> 6, c8 = (t & 63) * 8;
        int row = (mode == 0) ? (rowBase + idx * 8 + p) : (rowBase + p * 8 + idx);
        const float* qp = q + (size_t)row * ld + c8;
        const float* kp = k + (size_t)row * ld + c8;
        const float* vp = v + (size_t)row * ld + c8;
        *(float4*)(&qs[p][c8])     = *(const float4*)(qp);
        *(float4*)(&qs[p][c8 + 4]) = *(const float4*)(qp + 4);
        *(float4*)(&ks[p][c8])     = *(const float4*)(kp);
        *(float4*)(&ks[p][c8 + 4]) = *(const float4*)(kp + 4);
        *(float4*)(&vs[p][c8])     = *(const float4*)(vp);
        *(float4*)(&vs[p][c8 + 4]) = *(const float4*)(vp + 4);
    }
    __syncthreads();

    {
        int h = tid >> 6, l = tid & 63;
        int i = l >> 3, j = l & 7;
        const float* qrow = &qs[i][h * 128];
        const float* krow = &ks[j][h * 128];
        float s = 0.f;
#pragma unroll
        for (int d = 0; d < 128; d += 4) {
            float4 qa = *(const float4*)(qrow + d);
            float4 kb = *(const float4*)(krow + d);
            s += qa.x * kb.x + qa.y * kb.y + qa.z * kb.z + qa.w * kb.w;
        }
        sc[h][i][j] = s * 0.08838834764831845f;
    }
    __syncthreads();

    if (tid < 32) {
        int h = tid >> 3, i = tid & 7;
        float mx = -1e30f;
#pragma unroll
        for (int j = 0; j < 8; ++j) mx = fmaxf(mx, sc[h][i][j]);
        float e[8], sum = 0.f;
#pragma unroll
        for (int j = 0; j < 8; ++j) { e[j] = __expf(sc[h][i][j] - mx); sum += e[j]; }
        float inv = 1.f / sum;
#pragma unroll
        for (int j = 0; j < 8; ++j) sc[h][i][j] = e[j] * inv;
    }
    __syncthreads();

    if (tid < 32) {
        int h = tid >> 3, j = tid & 7;
        float s = 0.f;
#pragma unroll
        for (int i = 0; i < 8; ++i) s += sc[h][i][j];
        wb[h][j] = s * 0.125f;
    }
    __syncthreads();

    {
        int orow = g * 16 + mode * 8 + idx;
        for (int c = tid; c < 512; c += 256) {
            int h = c >> 7;
            float o = 0.f;
#pragma unroll
            for (int j = 0; j < 8; ++j) o += wb[h][j] * vs[j][c];
            abar[(size_t)orow * 512 + c] = __float2bfloat16(o);
        }
    }
}

// ---------------------------------------------------------------------------

extern "C" void kernel_launch(void* const* d_in, const int* in_sizes, int n_in,
                              void* d_out, int out_size, void* d_ws, size_t ws_size,
                              hipStream_t stream)
{
    const float* Ao   = (const float*)d_in[0];   // (8,512,512)
    const float* srco = (const float*)d_in[1];   // (4096,1024)
    const float* Ar   = (const float*)d_in[2];   // (8,2048,2048)
    const float* srcr = (const float*)d_in[3];   // (16384,300)
    const float* Wo1  = (const float*)d_in[4];   // (1024,1024)
    const float* Wo2  = (const float*)d_in[5];   // (1024,512)
    const float* Wr1  = (const float*)d_in[6];   // (300,1024)
    const float* Wr2  = (const float*)d_in[7];   // (1024,512)
    const float* Wq   = (const float*)d_in[8];
    const float* bq   = (const float*)d_in[9];
    const float* Wk   = (const float*)d_in[10];
    const float* bk   = (const float*)d_in[11];
    const float* Wv   = (const float*)d_in[12];
    const float* bv   = (const float*)d_in[13];
    const float* Wp   = (const float*)d_in[14];
    const float* bp   = (const float*)d_in[15];
    const float* We   = (const float*)d_in[16];  // (1024,512)
    const float* be   = (const float*)d_in[17];
    float* out = (float*)d_out;                  // (4096,512) fp32

    char* ws = (char*)d_ws;
    // R0 (0, 67.1M):      HR planes -> later QKV fp32 (16384x1536, spans R0+R1)
    // R1 (67.1M, 33.5M):  T2Rf fp32 -> later QKV tail
    // R2 (100.7M, 33.5M): U planes, then T2RT planes, then bqkv, then o-pool
    // R3 (134.2M, 33.5M): GR planes (o-pool tail spans into R3 after qkv)
    // R4 (167.8M, 25.2M): XPT planes -> later ABAR (bf16, 4.2M)
    // R5 (193.0M, 6.6M):  WPT planes, Wr2T planes, Wqkv concat planes
    // R6 (199.5M, 134.2M): OPTIONAL Ar planes (only if ws_size permits)
    const size_t R0 = 0;
    const size_t R1 = 67108864;
    const size_t R2 = 100663296;
    const size_t R3 = 134217728;
    const size_t R4 = 167772160;
    const size_t R5 = 192937984;
    const size_t R6 = 199491584;

    __hip_bfloat16* HRh = (__hip_bfloat16*)(ws + R0);
    __hip_bfloat16* HRl = HRh + 16777216;            // 16384x1024 each
    float* QKV  = (float*)(ws + R0);                 // 16384x1536 fp32 (100.7M)
    float* T2Rf = (float*)(ws + R1);                 // 16384x512 fp32
    __hip_bfloat16* Uh = (__hip_bfloat16*)(ws + R2);
    __hip_bfloat16* Ul = Uh + 6291456;               // 16384x384 each
    __hip_bfloat16* T2RTh = (__hip_bfloat16*)(ws + R2);
    __hip_bfloat16* T2RTl = T2RTh + 8388608;         // 8x512x2048 each
    float* bqkv = (float*)(ws + R2);                 // 1536 f32 (after T2RT dead)
    __hip_bfloat16* GRh = (__hip_bfloat16*)(ws + R3);
    __hip_bfloat16* GRl = GRh + 8388608;             // 16384x512 each
    __hip_bfloat16* XPTh = (__hip_bfloat16*)(ws + R4);
    __hip_bfloat16* XPTl = XPTh + 6291456;           // 8x384x2048 each
    __hip_bfloat16* ABAR = (__hip_bfloat16*)(ws + R4);
    __hip_bfloat16* WPTh = (__hip_bfloat16*)(ws + R5);               // 1024x320
    __hip_bfloat16* WPTl = WPTh + 327680;
    __hip_bfloat16* Wr2Th = (__hip_bfloat16*)(ws + R5 + 1310720);    // 512x1024
    __hip_bfloat16* Wr2Tl = Wr2Th + 524288;
    __hip_bfloat16* WqkvTh = (__hip_bfloat16*)(ws + R5 + 3407872);   // 1536x512
    __hip_bfloat16* WqkvTl = (__hip_bfloat16*)(ws + R5 + 4980736);   // 1536x512
    __hip_bfloat16* Arh = (__hip_bfloat16*)(ws + R6);                // 8x2048x2048
    __hip_bfloat16* Arl = Arh + 33554432;
    const bool haveArPlanes = ws_size >= R6 + 2ull * 67108864ull;    // 333.7MB

    // o-branch bf16 pool at R2 (valid after attn inputs consumed; spans R3)
    __hip_bfloat16* TO     = (__hip_bfloat16*)(ws + R2 + 0);
    __hip_bfloat16* HO     = (__hip_bfloat16*)(ws + R2 + 8388608);
    __hip_bfloat16* T2O    = (__hip_bfloat16*)(ws + R2 + 16777216);
    __hip_bfloat16* CAT    = (__hip_bfloat16*)(ws + R2 + 20971520);
    __hip_bfloat16* srcoB  = (__hip_bfloat16*)(ws + R2 + 29360128);
    __hip_bfloat16* AoB    = (__hip_bfloat16*)(ws + R2 + 37748736);
    __hip_bfloat16* Wo1BT  = (__hip_bfloat16*)(ws + R2 + 41943040);  // (1024,1024) T
    __hip_bfloat16* Wo2BT  = (__hip_bfloat16*)(ws + R2 + 44040192);  // (512,1024) T
    __hip_bfloat16* WeBT   = (__hip_bfloat16*)(ws + R2 + 45088768);  // (512,1024) T
    __hip_bfloat16* WpBT   = (__hip_bfloat16*)(ws + R2 + 46137344);  // (512,512) T

    dim3 blk(256);
    auto cvt = [&](const float* s, __hip_bfloat16* d, int n) {
        convert_kernel<<<dim3((n / 4 + 255) / 256), blk, 0, stream>>>(s, d, n / 4);
    };

    // ---- transposes (emit hi/lo planes) ----
    padtrans_split<<<dim3(6, 32, 8), blk, 0, stream>>>(srcr, XPTh, XPTl, 2048, 300, 2048, 384);
    padtrans_split<<<dim3(16, 5, 1), blk, 0, stream>>>(Wr1, WPTh, WPTl, 300, 1024, 320, 1024);
    padtrans_split<<<dim3(8, 16, 1), blk, 0, stream>>>(Wr2, Wr2Th, Wr2Tl, 1024, 512, 1024, 512);
    // concatenated Wqkv^T planes: rows 0-511=Wq^T, 512-1023=Wk^T, 1024-1535=Wv^T
    padtrans_split<<<dim3(8, 8, 1), blk, 0, stream>>>(Wq, WqkvTh, WqkvTl, 512, 512, 512, 512);
    padtrans_split<<<dim3(8, 8, 1), blk, 0, stream>>>(Wk, WqkvTh + 262144, WqkvTl + 262144, 512, 512, 512, 512);
    padtrans_split<<<dim3(8, 8, 1), blk, 0, stream>>>(Wv, WqkvTh + 524288, WqkvTl + 524288, 512, 512, 512, 512);

    // ---- r-branch (split precision, planes in memory) ----
    if (haveArPlanes) {
        split_kernel<<<dim3(32768), blk, 0, stream>>>(Ar, Arh, Arl, 8388608);
        // U = Ar@XP + XP -> U planes
        gemm_planes<<<dim3(3, 16, 8), blk, 0, stream>>>(
            Arh, Arl, 2048LL * 2048, 2048, XPTh, XPTl, 384LL * 2048, 2048,
            Uh, Ul, 2048LL * 384, 384,
            nullptr, 0, 0, XPTh, XPTl, 384LL * 2048, 2048,
            nullptr, 2048, 0, 1);
    } else {
        gemm_asplit<<<dim3(3, 16, 8), blk, 0, stream>>>(
            Ar, 2048LL * 2048, 2048, XPTh, XPTl, 384LL * 2048, 2048,
            Uh, Ul, 2048LL * 384, 384,
            nullptr, 0, 0, XPTh, XPTl, 384LL * 2048, 2048,
            2048, 0);
    }
    // HR = relu(U@WP)  (16384x320 @ 320x1024) -> HR planes
    gemm_planes<<<dim3(8, 128, 1), blk, 0, stream>>>(
        Uh, Ul, 0, 384, WPTh, WPTl, 0, 320,
        HRh, HRl, 0, 1024,
        nullptr, 0, 0, nullptr, nullptr, 0, 0,
        nullptr, 320, 1, 1);
    // T2R = HR@Wr2  (16384x1024 @ 1024x512) -> fp32 (addN + transpose src)
    gemm_planes<<<dim3(4, 128, 1), blk, 0, stream>>>(
        HRh, HRl, 0, 1024, Wr2Th, Wr2Tl, 0, 1024,
        T2Rf, nullptr, 0, 512,
        nullptr, 0, 0, nullptr, nullptr, 0, 0,
        nullptr, 1024, 0, 0);
    // T2RT (8,512,2048) planes from T2Rf viewed (8,2048,512)
    padtrans_split<<<dim3(8, 32, 8), blk, 0, stream>>>(T2Rf, T2RTh, T2RTl, 2048, 512, 2048, 512);
    // GR = relu(Ar@T2R + T2R) -> GR planes
    if (haveArPlanes) {
        gemm_planes<<<dim3(4, 16, 8), blk, 0, stream>>>(
            Arh, Arl, 2048LL * 2048, 2048, T2RTh, T2RTl, 512LL * 2048, 2048,
            GRh, GRl, 2048LL * 512, 512,
            T2Rf, 2048LL * 512, 512, nullptr, nullptr, 0, 0,
            nullptr, 2048, 1, 1);
    } else {
        gemm_asplit<<<dim3(4, 16, 8), blk, 0, stream>>>(
            Ar, 2048LL * 2048, 2048, T2RTh, T2RTl, 512LL * 2048, 2048,
            GRh, GRl, 2048LL * 512, 512,
            T2Rf, 2048LL * 512, 512, nullptr, nullptr, 0, 0,
            2048, 1);
    }
    // fused q|k|v = GR @ [Wq|Wk|Wv] + [bq|bk|bv]  (16384x1536x512) -> QKV fp32
    // (T2RT planes dead -> bqkv at R2; HR planes + T2Rf dead -> QKV at R0+R1)
    bcat_kernel<<<dim3(6), blk, 0, stream>>>(bq, bk, bv, bqkv);
    gemm_planes<<<dim3(12, 128, 1), blk, 0, stream>>>(
        GRh, GRl, 0, 512, WqkvTh, WqkvTl, 0, 512,
        QKV, nullptr, 0, 1536,
        nullptr, 0, 0, nullptr, nullptr, 0, 0,
        bqkv, 512, 0, 0);
    // fused attention + query-mean -> ABAR bf16 (4096,512); XPT planes dead
    attn_kernel<<<dim3(2048, 2), blk, 0, stream>>>(QKV, QKV + 512, QKV + 1024, 1536, ABAR);

    // ---- o-branch (bf16; weight-B GEMMs on async bf16t path) ----
    cvt(srco, srcoB, 4194304);
    cvt(Ao, AoB, 2097152);
    padtrans_bf16<<<dim3(16, 16, 1), blk, 0, stream>>>(Wo1, Wo1BT, 1024, 1024, 1024, 1024);
    padtrans_bf16<<<dim3(8, 16, 1), blk, 0, stream>>>(Wo2, Wo2BT, 1024, 512, 1024, 512);
    padtrans_bf16<<<dim3(8, 16, 1), blk, 0, stream>>>(We, WeBT, 1024, 512, 1024, 512);
    padtrans_bf16<<<dim3(8, 8, 1), blk, 0, stream>>>(Wp, WpBT, 512, 512, 512, 512);
    // TO = srco @ Wo1  (4096x1024x1024)
    gemm_bf16t<<<dim3(8, 32, 1), blk, 0, stream>>>(srcoB, 1024, Wo1BT, 1024,
        TO, 1024, nullptr, 1024, 0);
    // HO = relu(Ao@TO + TO)  batched 8
    gemm_bf16<<<dim3(8, 4, 8), blk, 0, stream>>>(AoB, 512LL * 512, 512, TO, 512LL * 1024, 1024,
        HO, 512LL * 1024, 1024, TO, 512LL * 1024, 1024, nullptr, 512, 1, 0);
    // T2O = HO @ Wo2  (4096x512x1024)
    gemm_bf16t<<<dim3(4, 32, 1), blk, 0, stream>>>(HO, 1024, Wo2BT, 1024,
        T2O, 512, nullptr, 1024, 0);
    // g_o = relu(Ao@T2O + T2O) -> CAT right half
    gemm_bf16<<<dim3(4, 4, 8), blk, 0, stream>>>(AoB, 512LL * 512, 512, T2O, 512LL * 512, 512,
        (void*)(CAT + 512), 512LL * 1024, 1024, T2O, 512LL * 512, 512, nullptr, 512, 1, 0);
    // P = ABAR @ Wp + bp -> CAT left half
    gemm_bf16t<<<dim3(4, 32, 1), blk, 0, stream>>>(ABAR, 512, WpBT, 512,
        CAT, 1024, bp, 512, 0);
    // out = CAT @ We + be  -> fp32
    gemm_bf16t<<<dim3(4, 32, 1), blk, 0, stream>>>(CAT, 1024, WeBT, 1024,
        out, 512, be, 1024, 1);
}